// Round 1
// baseline (711.312 us; speedup 1.0000x reference)
//
#include <hip/hip_runtime.h>

#define H 160
#define W 160
#define HW 25600
#define BB 2
#define CC 3
#define LL 72
#define NKEYS 3000
#define KSPLIT 8
#define KEYS_PER_SPLIT 375   // 3000 / 8
#define TILE_KEYS 75
#define NPIX (BB * HW)       // 51200

// ---------------- Kernel 1: routing (Q·K^T argmax) ----------------
// grid = (NPIX/256, KSPLIT), block = 256. One thread = one pixel.
// Keys tiled through LDS; wave-uniform broadcast reads.
__global__ __launch_bounds__(256) void route_kernel(
    const float* __restrict__ queries,
    const float* __restrict__ keys,
    unsigned long long* __restrict__ best_packed)
{
    __shared__ float4 lds4[TILE_KEYS * 18];   // 75 keys x 72 f32 = 21.6 KB

    const int p  = blockIdx.x * 256 + threadIdx.x;   // pixel id
    const int b  = p / HW;
    const int hw = p - b * HW;
    const float* qp = queries + (size_t)b * LL * HW + hw;

    // load the 72 query features for this pixel into registers (coalesced)
    float q[LL];
#pragma unroll
    for (int l = 0; l < LL; ++l) q[l] = qp[(size_t)l * HW];

    const int kbase0 = blockIdx.y * KEYS_PER_SPLIT;
    float best = -1e30f;
    int   bidx = 0;
    const float4* keys4 = (const float4*)keys;

    for (int t0 = 0; t0 < KEYS_PER_SPLIT; t0 += TILE_KEYS) {
        const int kb = kbase0 + t0;
        __syncthreads();
        for (int t = threadIdx.x; t < TILE_KEYS * 18; t += 256)
            lds4[t] = keys4[(size_t)kb * 18 + t];
        __syncthreads();

#pragma unroll 2
        for (int kk = 0; kk < TILE_KEYS; ++kk) {
            float a0 = 0.f, a1 = 0.f, a2 = 0.f, a3 = 0.f;
#pragma unroll
            for (int l4 = 0; l4 < 18; ++l4) {
                float4 kv = lds4[kk * 18 + l4];
                a0 += q[l4 * 4 + 0] * kv.x;
                a1 += q[l4 * 4 + 1] * kv.y;
                a2 += q[l4 * 4 + 2] * kv.z;
                a3 += q[l4 * 4 + 3] * kv.w;
            }
            const float s = (a0 + a1) + (a2 + a3);
            const int key = kb + kk;
            if (s > best) { best = s; bidx = key; }   // strict > : first occurrence
        }
    }

    // monotonic pack: larger sim -> larger u64; ties -> smaller idx wins
    unsigned int fb = __float_as_uint(best);
    unsigned int tm = (fb & 0x80000000u) ? ~fb : (fb | 0x80000000u);
    unsigned long long packed =
        ((unsigned long long)tm << 32) | (unsigned int)(~bidx);
    atomicMax(&best_packed[p], packed);
}

// ------- Kernel 2: gather + dynamic 5x5 conv + pixel shuffle -------
// grid = NPIX/256, block = 256. One thread = one input pixel -> 48 outputs.
__global__ __launch_bounds__(256) void conv_kernel(
    const float* __restrict__ x,
    const float* __restrict__ values,
    const unsigned long long* __restrict__ best_packed,
    float* __restrict__ out)
{
    const int p  = blockIdx.x * 256 + threadIdx.x;
    const int b  = p / HW;
    const int hw = p - b * HW;
    const int h  = hw / W;
    const int w  = hw - h * W;

    const int idx = (int)(~(unsigned int)(best_packed[p] & 0xffffffffu));

    // reflect-padded 5x5 patch for each of the 3 channels
    float patch[CC][25];
#pragma unroll
    for (int i = 0; i < 5; ++i) {
        int r = h + i - 2;
        r = (r < 0) ? -r : ((r >= H) ? (2 * H - 2 - r) : r);
#pragma unroll
        for (int j = 0; j < 5; ++j) {
            int cidx = w + j - 2;
            cidx = (cidx < 0) ? -cidx : ((cidx >= W) ? (2 * W - 2 - cidx) : cidx);
#pragma unroll
            for (int c = 0; c < CC; ++c)
                patch[c][i * 5 + j] = x[((size_t)(b * CC + c) * H + r) * W + cidx];
        }
    }

    const float* vbase = values + (size_t)idx * 400;   // [16][25]

    float acc[CC][16];
#pragma unroll
    for (int c = 0; c < CC; ++c)
#pragma unroll
        for (int si = 0; si < 16; ++si) acc[c][si] = 0.f;

#pragma unroll
    for (int si = 0; si < 16; ++si) {
        float v[25];
#pragma unroll
        for (int kk = 0; kk < 25; ++kk) v[kk] = vbase[si * 25 + kk];
#pragma unroll
        for (int c = 0; c < CC; ++c) {
            float a = 0.f;
#pragma unroll
            for (int kk = 0; kk < 25; ++kk) a += patch[c][kk] * v[kk];
            acc[c][si] = a;
        }
    }

    // pixel shuffle: out[b][c][h*4+sy][w*4+sx], float4 over sx
#pragma unroll
    for (int c = 0; c < CC; ++c) {
#pragma unroll
        for (int sy = 0; sy < 4; ++sy) {
            float4 o = make_float4(acc[c][sy * 4 + 0], acc[c][sy * 4 + 1],
                                   acc[c][sy * 4 + 2], acc[c][sy * 4 + 3]);
            size_t off = ((size_t)(b * CC + c) * (H * 4) + (h * 4 + sy)) * (size_t)(W * 4)
                         + (size_t)w * 4;
            *(float4*)(&out[off]) = o;
        }
    }
}

extern "C" void kernel_launch(void* const* d_in, const int* in_sizes, int n_in,
                              void* d_out, int out_size, void* d_ws, size_t ws_size,
                              hipStream_t stream) {
    const float* x       = (const float*)d_in[0];
    const float* queries = (const float*)d_in[1];
    const float* keys    = (const float*)d_in[2];
    const float* values  = (const float*)d_in[3];
    float* out = (float*)d_out;
    unsigned long long* packed = (unsigned long long*)d_ws;

    hipMemsetAsync(d_ws, 0, (size_t)NPIX * sizeof(unsigned long long), stream);
    route_kernel<<<dim3(NPIX / 256, KSPLIT), 256, 0, stream>>>(queries, keys, packed);
    conv_kernel<<<NPIX / 256, 256, 0, stream>>>(x, values, packed, out);
}

// Round 2
// 392.499 us; speedup vs baseline: 1.8123x; 1.8123x over previous
//
#include <hip/hip_runtime.h>

#define H 160
#define W 160
#define HW 25600
#define BB 2
#define CC 3
#define LL 72
#define NKEYS 3000
#define KSPLIT 12
#define KEYS_PER_SPLIT 250   // 3000 / 12
#define NPIX (BB * HW)       // 51200

// ---------------- Kernel 1: routing (Q·K^T argmax) ----------------
// grid = (NPIX/256, KSPLIT), block = 256. One thread = one pixel.
// Keys are wave-uniform -> scalar (SMEM) loads; FMAs are v_fmac(s,v,v).
__global__ __launch_bounds__(256) void route_kernel(
    const float* __restrict__ queries,
    const float* __restrict__ keys,
    unsigned long long* __restrict__ best_packed)
{
    const int p  = blockIdx.x * 256 + threadIdx.x;   // pixel id
    const int b  = p / HW;
    const int hw = p - b * HW;
    const float* __restrict__ qp = queries + (size_t)b * LL * HW + hw;

    // 72 query features for this pixel -> VGPRs (coalesced across lanes)
    float q[LL];
#pragma unroll
    for (int l = 0; l < LL; ++l) q[l] = qp[(size_t)l * HW];

    const int k0 = blockIdx.y * KEYS_PER_SPLIT;
    float best = -3.0e38f;
    int   bidx = 0;

#pragma unroll 2
    for (int kk = 0; kk < KEYS_PER_SPLIT; ++kk) {
        const int key = k0 + kk;
        const float* __restrict__ kp = keys + (size_t)key * LL;  // uniform addr
        float a0 = 0.f, a1 = 0.f, a2 = 0.f, a3 = 0.f;
#pragma unroll
        for (int l = 0; l < 18; ++l) {
            a0 = fmaf(q[4 * l + 0], kp[4 * l + 0], a0);
            a1 = fmaf(q[4 * l + 1], kp[4 * l + 1], a1);
            a2 = fmaf(q[4 * l + 2], kp[4 * l + 2], a2);
            a3 = fmaf(q[4 * l + 3], kp[4 * l + 3], a3);
        }
        const float s = (a0 + a1) + (a2 + a3);
        if (s > best) { best = s; bidx = key; }   // strict > : first occurrence
    }

    // monotonic pack: larger sim -> larger u64; ties -> smaller idx wins
    unsigned int fb = __float_as_uint(best);
    unsigned int tm = (fb & 0x80000000u) ? ~fb : (fb | 0x80000000u);
    unsigned long long packed =
        ((unsigned long long)tm << 32) | (unsigned int)(~bidx);
    atomicMax(&best_packed[p], packed);
}

// ------- Kernel 2: gather + dynamic 5x5 conv + pixel shuffle -------
// grid = NPIX/256, block = 256. One thread = one input pixel -> 48 outputs.
__global__ __launch_bounds__(256) void conv_kernel(
    const float* __restrict__ x,
    const float* __restrict__ values,
    const unsigned long long* __restrict__ best_packed,
    float* __restrict__ out)
{
    const int p  = blockIdx.x * 256 + threadIdx.x;
    const int b  = p / HW;
    const int hw = p - b * HW;
    const int h  = hw / W;
    const int w  = hw - h * W;

    const int idx = (int)(~(unsigned int)(best_packed[p] & 0xffffffffu));

    // reflect-padded 5x5 patch for each of the 3 channels
    float patch[CC][25];
#pragma unroll
    for (int i = 0; i < 5; ++i) {
        int r = h + i - 2;
        r = (r < 0) ? -r : ((r >= H) ? (2 * H - 2 - r) : r);
#pragma unroll
        for (int j = 0; j < 5; ++j) {
            int cidx = w + j - 2;
            cidx = (cidx < 0) ? -cidx : ((cidx >= W) ? (2 * W - 2 - cidx) : cidx);
#pragma unroll
            for (int c = 0; c < CC; ++c)
                patch[c][i * 5 + j] = x[((size_t)(b * CC + c) * H + r) * W + cidx];
        }
    }

    const float* vbase = values + (size_t)idx * 400;   // [16][25]

    float acc[CC][16];
#pragma unroll
    for (int c = 0; c < CC; ++c)
#pragma unroll
        for (int si = 0; si < 16; ++si) acc[c][si] = 0.f;

#pragma unroll
    for (int si = 0; si < 16; ++si) {
        float v[25];
#pragma unroll
        for (int kk = 0; kk < 25; ++kk) v[kk] = vbase[si * 25 + kk];
#pragma unroll
        for (int c = 0; c < CC; ++c) {
            float a = 0.f;
#pragma unroll
            for (int kk = 0; kk < 25; ++kk) a += patch[c][kk] * v[kk];
            acc[c][si] = a;
        }
    }

    // pixel shuffle: out[b][c][h*4+sy][w*4+sx], float4 over sx
#pragma unroll
    for (int c = 0; c < CC; ++c) {
#pragma unroll
        for (int sy = 0; sy < 4; ++sy) {
            float4 o = make_float4(acc[c][sy * 4 + 0], acc[c][sy * 4 + 1],
                                   acc[c][sy * 4 + 2], acc[c][sy * 4 + 3]);
            size_t off = ((size_t)(b * CC + c) * (H * 4) + (h * 4 + sy)) * (size_t)(W * 4)
                         + (size_t)w * 4;
            *(float4*)(&out[off]) = o;
        }
    }
}

extern "C" void kernel_launch(void* const* d_in, const int* in_sizes, int n_in,
                              void* d_out, int out_size, void* d_ws, size_t ws_size,
                              hipStream_t stream) {
    const float* x       = (const float*)d_in[0];
    const float* queries = (const float*)d_in[1];
    const float* keys    = (const float*)d_in[2];
    const float* values  = (const float*)d_in[3];
    float* out = (float*)d_out;
    unsigned long long* packed = (unsigned long long*)d_ws;

    hipMemsetAsync(d_ws, 0, (size_t)NPIX * sizeof(unsigned long long), stream);
    route_kernel<<<dim3(NPIX / 256, KSPLIT), 256, 0, stream>>>(queries, keys, packed);
    conv_kernel<<<NPIX / 256, 256, 0, stream>>>(x, values, packed, out);
}

// Round 3
// 338.127 us; speedup vs baseline: 2.1037x; 1.1608x over previous
//
#include <hip/hip_runtime.h>

#define H 160
#define W 160
#define HW 25600
#define BB 2
#define CC 3
#define LL 72
#define NKEYS 3000
#define NKPAD 3008
#define NT 94          // key tiles of 32
#define NG 47          // groups of 2 tiles
#define NPIX (BB * HW) // 51200

// error-window constants (rigorous bound ~3e-5 * S * Kmax; 2.3x margin)
#define CERR 7e-5f
#define ABSG 1.5e-3f

typedef __attribute__((ext_vector_type(8))) short bf8v;   // 8 bf16 (4 VGPR)
typedef __attribute__((ext_vector_type(16))) float f16v;  // MFMA 32x32 acc

union FU { uint4 u4; bf8v v; };

// ws layout (bytes):
//   [0..3]  count   [4..7] kmax bits
//   [1024 .. +962560)      kfrag: NT*5ksteps*2splits*64lanes*16B
//   [963584 .. +204800)    cleanup list (u32 pixel ids)
//   [1168384 .. +204800)   idx_buf (i32 per pixel)
#define WS_KFRAG 1024
#define WS_LIST  963584
#define WS_IDX   1168384

__device__ inline unsigned bf16rn(float f) {  // RN-even bf16 bits (low 16)
    unsigned u = __float_as_uint(f);
    return (u + 0x7FFFu + ((u >> 16) & 1u)) >> 16;
}

// ---------- kprep: keys -> bf16 hi/lo MFMA A-fragment layout + Kmax ----------
// grid = NT blocks x 64 threads. A-frag: lane holds K[row=lane&31][k=(lane>>5)*8+i]
__global__ __launch_bounds__(64) void kprep_kernel(
    const float* __restrict__ keys, unsigned* __restrict__ ctrl,
    uint4* __restrict__ kfg)
{
    const int tile = blockIdx.x;
    const int lane = threadIdx.x;
    const int key  = tile * 32 + (lane & 31);
    const int half = lane >> 5;
    const bool kv  = (key < NKEYS);
    float kmax = 0.f;
#pragma unroll
    for (int ks = 0; ks < 5; ++ks) {
        unsigned wh[4], wl[4];
#pragma unroll
        for (int j = 0; j < 4; ++j) {
            const int l0 = ks * 16 + half * 8 + 2 * j;
            float v0 = (kv && l0     < LL) ? keys[(size_t)key * LL + l0]     : 0.f;
            float v1 = (kv && l0 + 1 < LL) ? keys[(size_t)key * LL + l0 + 1] : 0.f;
            kmax = fmaxf(kmax, fmaxf(fabsf(v0), fabsf(v1)));
            unsigned h0 = bf16rn(v0), h1 = bf16rn(v1);
            float r0 = v0 - __uint_as_float(h0 << 16);
            float r1 = v1 - __uint_as_float(h1 << 16);
            wh[j] = h0 | (h1 << 16);
            wl[j] = bf16rn(r0) | (bf16rn(r1) << 16);
        }
        const int base = tile * 640 + (ks * 2) * 64 + lane;
        kfg[base]      = make_uint4(wh[0], wh[1], wh[2], wh[3]);
        kfg[base + 64] = make_uint4(wl[0], wl[1], wl[2], wl[3]);
    }
#pragma unroll
    for (int m = 32; m >= 1; m >>= 1)
        kmax = fmaxf(kmax, __shfl_xor(kmax, m));
    if (lane == 0) atomicMax(&ctrl[1], __float_as_uint(kmax));
}

// ---------------- route: 3-product bf16 MFMA + packed top-2 ----------------
template<bool LAST>
__device__ inline void do_tile(const uint4* __restrict__ kb, int t, int tileIdx,
                               const FU* __restrict__ qh, const FU* __restrict__ ql,
                               int lane, int hb, unsigned& m1, unsigned& m2)
{
    f16v acc;
#pragma unroll
    for (int r = 0; r < 16; ++r) acc[r] = 0.f;
#pragma unroll
    for (int ks = 0; ks < 5; ++ks) {
        FU kh, kl;
        kh.u4 = kb[(t * 5 + ks) * 128 + lane];
        kl.u4 = kb[(t * 5 + ks) * 128 + 64 + lane];
        acc = __builtin_amdgcn_mfma_f32_32x32x16_bf16(kh.v, qh[ks].v, acc, 0, 0, 0);
        acc = __builtin_amdgcn_mfma_f32_32x32x16_bf16(kh.v, ql[ks].v, acc, 0, 0, 0);
        acc = __builtin_amdgcn_mfma_f32_32x32x16_bf16(kl.v, qh[ks].v, acc, 0, 0, 0);
    }
    const int kc0 = tileIdx * 32;
    const int NR = LAST ? 12 : 16;   // last tile rows 24..31 are pad keys
#pragma unroll
    for (int r = 0; r < NR; ++r) {
        float s = acc[r] + 64.0f;
        s = fmaxf(s, 1.0f);
        unsigned u = __float_as_uint(s);
        unsigned key = (unsigned)(kc0 + ((r & 3) + 8 * (r >> 2)) + hb);
        unsigned pk = (u & 0xFFFFF000u) | key;
        m2 = max(m2, min(m1, pk));
        m1 = max(m1, pk);
    }
}

// grid = 400 blocks x 256 (4 waves, each wave = 32 pixels across all keys)
__global__ __launch_bounds__(256) void route_kernel(
    const float* __restrict__ queries,
    const uint4* __restrict__ kfg,
    unsigned* __restrict__ ctrl,
    unsigned* __restrict__ list,
    int* __restrict__ idx_buf)
{
    __shared__ uint4 kbuf[2][1280];   // 2 x (2 tiles x 5 ksteps x 2 splits x 64) = 40 KB

    const int tid  = threadIdx.x;
    const int lane = tid & 63;
    const int wid  = tid >> 6;
    const int hv   = lane >> 5;       // k-half
    const int hb   = 4 * hv;          // C-row offset
    const int pbase = blockIdx.x * 128 + wid * 32;
    const int p    = pbase + (lane & 31);
    const int b    = p / HW;
    const int hw   = p - b * HW;
    const float* __restrict__ qp = queries + (size_t)b * LL * HW + hw;

    // build loop-invariant Q B-fragments (col=lane&31=pixel, k=(lane>>5)*8+i)
    FU qh[5], ql[5];
    float Ssum = 0.f;
#pragma unroll
    for (int ks = 0; ks < 5; ++ks) {
        unsigned wh[4], wl[4];
#pragma unroll
        for (int j = 0; j < 4; ++j) {
            const int l0 = ks * 16 + hv * 8 + 2 * j;
            float v0 = (l0     < LL) ? qp[(size_t)l0 * HW]       : 0.f;
            float v1 = (l0 + 1 < LL) ? qp[(size_t)(l0 + 1) * HW] : 0.f;
            Ssum += fabsf(v0) + fabsf(v1);
            unsigned h0 = bf16rn(v0), h1 = bf16rn(v1);
            float r0 = v0 - __uint_as_float(h0 << 16);
            float r1 = v1 - __uint_as_float(h1 << 16);
            wh[j] = h0 | (h1 << 16);
            wl[j] = bf16rn(r0) | (bf16rn(r1) << 16);
        }
        qh[ks].u4 = make_uint4(wh[0], wh[1], wh[2], wh[3]);
        ql[ks].u4 = make_uint4(wl[0], wl[1], wl[2], wl[3]);
    }
    const float S_p = Ssum + __shfl_xor(Ssum, 32);   // full sum over 72
    const float kmax = __uint_as_float(ctrl[1]);

    unsigned m1 = 0u, m2 = 0u;

    // prologue: stage group 0
#pragma unroll
    for (int j = 0; j < 5; ++j)
        kbuf[0][tid + j * 256] = kfg[tid + j * 256];
    __syncthreads();

    for (int g = 0; g < NG; ++g) {
        const int cur = g & 1;
        if (g < NG - 1) {
#pragma unroll
            for (int j = 0; j < 5; ++j)
                kbuf[cur ^ 1][tid + j * 256] = kfg[(size_t)(g + 1) * 1280 + tid + j * 256];
        }
        const uint4* kb = kbuf[cur];
        do_tile<false>(kb, 0, 2 * g, qh, ql, lane, hb, m1, m2);
        if (g == NG - 1) do_tile<true >(kb, 1, 2 * g + 1, qh, ql, lane, hb, m1, m2);
        else             do_tile<false>(kb, 1, 2 * g + 1, qh, ql, lane, hb, m1, m2);
        __syncthreads();
    }

    // merge key-row halves (lane p <-> lane p+32 hold same pixel)
    unsigned om1 = (unsigned)__shfl_xor((int)m1, 32);
    unsigned om2 = (unsigned)__shfl_xor((int)m2, 32);
    unsigned M1 = max(m1, om1);
    unsigned M2 = max(min(m1, om1), max(m2, om2));

    // certainty test: quantized gap vs rigorous error window
    unsigned gap = (M1 >> 12) - (M2 >> 12);
    int E = (int)((M1 >> 23) & 0xFFu);
    float dp = CERR * S_p * kmax + ABSG;
    float scale = __uint_as_float((unsigned)(138 - E + 127) << 23);  // 2^(138-E)
    float thr = 2.0f * dp * scale + 3.0f;
    bool certain = ((float)gap > thr);

    if ((lane & 32) == 0) {
        if (certain) idx_buf[p] = (int)(M1 & 0xFFFu);
        else { unsigned pos = atomicAdd(&ctrl[0], 1u); list[pos] = (unsigned)p; }
    }
}

// ---------------- cleanup: exact f32 rescore of uncertain pixels ----------------
// grid = 6400 blocks x 256; 8 pixels/block, 32 lanes per pixel.
__global__ __launch_bounds__(256) void cleanup_kernel(
    const float* __restrict__ queries, const float* __restrict__ keys,
    const unsigned* __restrict__ ctrl, const unsigned* __restrict__ list,
    int* __restrict__ idx_buf)
{
    __shared__ float qlds[8][72];
    const unsigned count = ctrl[0];
    const unsigned base = blockIdx.x * 8;
    if (base >= count) return;
    const int npx = (int)min(8u, count - base);

    for (int t = threadIdx.x; t < npx * 72; t += 256) {
        int slot = t / 72, l = t - slot * 72;
        int p = (int)list[base + slot];
        int b = p / HW, hw = p - b * HW;
        qlds[slot][l] = queries[((size_t)b * LL + l) * HW + hw];
    }
    __syncthreads();

    const int slot = threadIdx.x >> 5, ln = threadIdx.x & 31;
    if (slot >= npx) return;
    const int p = (int)list[base + slot];

    float qreg[72];
#pragma unroll
    for (int l = 0; l < 72; ++l) qreg[l] = qlds[slot][l];

    float best = -3.0e38f; int bidx = 0x7FFFFFFF;
    for (int n = ln; n < NKEYS; n += 32) {
        const float4* kr = (const float4*)(keys + (size_t)n * LL);
        float a0 = 0.f, a1 = 0.f, a2 = 0.f, a3 = 0.f;
#pragma unroll
        for (int j = 0; j < 18; ++j) {
            float4 kv = kr[j];
            a0 = fmaf(qreg[4 * j + 0], kv.x, a0);
            a1 = fmaf(qreg[4 * j + 1], kv.y, a1);
            a2 = fmaf(qreg[4 * j + 2], kv.z, a2);
            a3 = fmaf(qreg[4 * j + 3], kv.w, a3);
        }
        float s = (a0 + a1) + (a2 + a3);
        if (s > best || (s == best && n < bidx)) { best = s; bidx = n; }
    }
#pragma unroll
    for (int m = 16; m >= 1; m >>= 1) {
        float ob = __shfl_xor(best, m);
        int   oi = __shfl_xor(bidx, m);
        if (ob > best || (ob == best && oi < bidx)) { best = ob; bidx = oi; }
    }
    if (ln == 0) idx_buf[p] = bidx;
}

// ------- conv: gather + dynamic 5x5 conv + pixel shuffle (unchanged math) -------
__global__ __launch_bounds__(256) void conv_kernel(
    const float* __restrict__ x,
    const float* __restrict__ values,
    const int* __restrict__ idx_buf,
    float* __restrict__ out)
{
    const int p  = blockIdx.x * 256 + threadIdx.x;
    const int b  = p / HW;
    const int hw = p - b * HW;
    const int h  = hw / W;
    const int w  = hw - h * W;

    const int idx = idx_buf[p];

    float patch[CC][25];
#pragma unroll
    for (int i = 0; i < 5; ++i) {
        int r = h + i - 2;
        r = (r < 0) ? -r : ((r >= H) ? (2 * H - 2 - r) : r);
#pragma unroll
        for (int j = 0; j < 5; ++j) {
            int cidx = w + j - 2;
            cidx = (cidx < 0) ? -cidx : ((cidx >= W) ? (2 * W - 2 - cidx) : cidx);
#pragma unroll
            for (int c = 0; c < CC; ++c)
                patch[c][i * 5 + j] = x[((size_t)(b * CC + c) * H + r) * W + cidx];
        }
    }

    const float* vbase = values + (size_t)idx * 400;
    float acc[CC][16];
#pragma unroll
    for (int c = 0; c < CC; ++c)
#pragma unroll
        for (int si = 0; si < 16; ++si) acc[c][si] = 0.f;

#pragma unroll
    for (int si = 0; si < 16; ++si) {
        float v[25];
#pragma unroll
        for (int kk = 0; kk < 25; ++kk) v[kk] = vbase[si * 25 + kk];
#pragma unroll
        for (int c = 0; c < CC; ++c) {
            float a = 0.f;
#pragma unroll
            for (int kk = 0; kk < 25; ++kk) a += patch[c][kk] * v[kk];
            acc[c][si] = a;
        }
    }

#pragma unroll
    for (int c = 0; c < CC; ++c) {
#pragma unroll
        for (int sy = 0; sy < 4; ++sy) {
            float4 o = make_float4(acc[c][sy * 4 + 0], acc[c][sy * 4 + 1],
                                   acc[c][sy * 4 + 2], acc[c][sy * 4 + 3]);
            size_t off = ((size_t)(b * CC + c) * (H * 4) + (h * 4 + sy)) * (size_t)(W * 4)
                         + (size_t)w * 4;
            *(float4*)(&out[off]) = o;
        }
    }
}

extern "C" void kernel_launch(void* const* d_in, const int* in_sizes, int n_in,
                              void* d_out, int out_size, void* d_ws, size_t ws_size,
                              hipStream_t stream) {
    const float* x       = (const float*)d_in[0];
    const float* queries = (const float*)d_in[1];
    const float* keys    = (const float*)d_in[2];
    const float* values  = (const float*)d_in[3];
    float* out = (float*)d_out;

    char* ws = (char*)d_ws;
    unsigned* ctrl   = (unsigned*)ws;
    uint4*    kfg    = (uint4*)(ws + WS_KFRAG);
    unsigned* list   = (unsigned*)(ws + WS_LIST);
    int*      idxb   = (int*)(ws + WS_IDX);

    hipMemsetAsync(d_ws, 0, 8, stream);
    kprep_kernel<<<NT, 64, 0, stream>>>(keys, ctrl, kfg);
    route_kernel<<<NPIX / 128, 256, 0, stream>>>(queries, kfg, ctrl, list, idxb);
    cleanup_kernel<<<NPIX / 8, 256, 0, stream>>>(queries, keys, ctrl, list, idxb);
    conv_kernel<<<NPIX / 256, 256, 0, stream>>>(x, values, idxb, out);
}

// Round 4
// 243.041 us; speedup vs baseline: 2.9267x; 1.3912x over previous
//
#include <hip/hip_runtime.h>

#define H 160
#define W 160
#define HW 25600
#define BB 2
#define CC 3
#define LL 72
#define NKEYS 3000
#define NKPAD 3008
#define NT 94          // key tiles of 32
#define NG 47          // groups of 2 tiles
#define NPIX (BB * HW) // 51200

// rigorous split-bf16 error window: |approx-exact| <= ~2.2e-5 * S_p * kmax
// (omitted ql*kl + residual rounding + f32 accum, incl. numpy-side rounding).
// Constants carry ~1.4x margin.
#define CERR 3e-5f
#define ABSG 1e-3f

typedef __attribute__((ext_vector_type(8))) short bf8v;   // 8 bf16 (4 VGPR)
typedef __attribute__((ext_vector_type(16))) float f16v;  // MFMA 32x32 acc

union FU { uint4 u4; bf8v v; };

// ws layout (bytes):
//   [0..3]  count   [4..7] kmax bits
//   [1024 .. +962560)      kfrag: NT*5ksteps*2splits*64lanes*16B
//   [963584 .. +204800)    cleanup list (u32 pixel ids)
//   [1168384 .. +204800)   idx_buf (i32 per pixel)
#define WS_KFRAG 1024
#define WS_LIST  963584
#define WS_IDX   1168384

__device__ inline unsigned bf16rn(float f) {  // RN-even bf16 bits (low 16)
    unsigned u = __float_as_uint(f);
    return (u + 0x7FFFu + ((u >> 16) & 1u)) >> 16;
}

// ---------- kprep: keys -> bf16 hi/lo MFMA A-fragment layout + Kmax ----------
// grid = NT blocks x 64 threads. A-frag: lane holds K[row=lane&31][k=(lane>>5)*8+i]
__global__ __launch_bounds__(64) void kprep_kernel(
    const float* __restrict__ keys, unsigned* __restrict__ ctrl,
    uint4* __restrict__ kfg)
{
    const int tile = blockIdx.x;
    const int lane = threadIdx.x;
    const int key  = tile * 32 + (lane & 31);
    const int half = lane >> 5;
    const bool kv  = (key < NKEYS);
    float kmax = 0.f;
#pragma unroll
    for (int ks = 0; ks < 5; ++ks) {
        unsigned wh[4], wl[4];
#pragma unroll
        for (int j = 0; j < 4; ++j) {
            const int l0 = ks * 16 + half * 8 + 2 * j;
            float v0 = (kv && l0     < LL) ? keys[(size_t)key * LL + l0]     : 0.f;
            float v1 = (kv && l0 + 1 < LL) ? keys[(size_t)key * LL + l0 + 1] : 0.f;
            kmax = fmaxf(kmax, fmaxf(fabsf(v0), fabsf(v1)));
            unsigned h0 = bf16rn(v0), h1 = bf16rn(v1);
            float r0 = v0 - __uint_as_float(h0 << 16);
            float r1 = v1 - __uint_as_float(h1 << 16);
            wh[j] = h0 | (h1 << 16);
            wl[j] = bf16rn(r0) | (bf16rn(r1) << 16);
        }
        const int base = tile * 640 + (ks * 2) * 64 + lane;
        kfg[base]      = make_uint4(wh[0], wh[1], wh[2], wh[3]);
        kfg[base + 64] = make_uint4(wl[0], wl[1], wl[2], wl[3]);
    }
#pragma unroll
    for (int m = 32; m >= 1; m >>= 1)
        kmax = fmaxf(kmax, __shfl_xor(kmax, m));
    if (lane == 0) atomicMax(&ctrl[1], __float_as_uint(kmax));
}

// ---------------- route: 3-product bf16 MFMA + exact f32 top-2 ----------------
template<bool LAST>
__device__ inline void do_tile(const uint4* __restrict__ kb, int t, int tileIdx,
                               const FU* __restrict__ qh, const FU* __restrict__ ql,
                               int lane, int hb, float& b1, float& b2, int& bi)
{
    f16v acc;
#pragma unroll
    for (int r = 0; r < 16; ++r) acc[r] = 0.f;
#pragma unroll
    for (int ks = 0; ks < 5; ++ks) {
        FU kh, kl;
        kh.u4 = kb[(t * 5 + ks) * 128 + lane];
        kl.u4 = kb[(t * 5 + ks) * 128 + 64 + lane];
        acc = __builtin_amdgcn_mfma_f32_32x32x16_bf16(kh.v, qh[ks].v, acc, 0, 0, 0);
        acc = __builtin_amdgcn_mfma_f32_32x32x16_bf16(kh.v, ql[ks].v, acc, 0, 0, 0);
        acc = __builtin_amdgcn_mfma_f32_32x32x16_bf16(kl.v, qh[ks].v, acc, 0, 0, 0);
    }
    const int kb0 = tileIdx * 32 + hb;
    const int NR = LAST ? 12 : 16;   // last tile rows >=24 are pad keys
#pragma unroll
    for (int r = 0; r < NR; ++r) {
        const float s = acc[r];
        const int key = kb0 + ((r & 3) + 8 * (r >> 2));
        const bool gt = (s > b1);           // keys per lane are ascending
        b2 = fmaxf(b2, fminf(s, b1));
        b1 = fmaxf(b1, s);
        bi = gt ? key : bi;
    }
}

// grid = 400 blocks x 256 (4 waves, each wave = 32 pixels across all keys)
__global__ __launch_bounds__(256) void route_kernel(
    const float* __restrict__ queries,
    const uint4* __restrict__ kfg,
    unsigned* __restrict__ ctrl,
    unsigned* __restrict__ list,
    int* __restrict__ idx_buf)
{
    __shared__ uint4 kbuf[2][1280];   // 2 x (2 tiles x 5 ksteps x 2 splits x 64) = 40 KB

    const int tid  = threadIdx.x;
    const int lane = tid & 63;
    const int wid  = tid >> 6;
    const int hv   = lane >> 5;       // k-half
    const int hb   = 4 * hv;          // key-offset contribution of the k-half rows
    const int pbase = blockIdx.x * 128 + wid * 32;
    const int p    = pbase + (lane & 31);
    const int b    = p / HW;
    const int hw   = p - b * HW;
    const float* __restrict__ qp = queries + (size_t)b * LL * HW + hw;

    // build loop-invariant Q B-fragments (col=lane&31=pixel, k=(lane>>5)*8+i)
    FU qh[5], ql[5];
    float Ssum = 0.f;
#pragma unroll
    for (int ks = 0; ks < 5; ++ks) {
        unsigned wh[4], wl[4];
#pragma unroll
        for (int j = 0; j < 4; ++j) {
            const int l0 = ks * 16 + hv * 8 + 2 * j;
            float v0 = (l0     < LL) ? qp[(size_t)l0 * HW]       : 0.f;
            float v1 = (l0 + 1 < LL) ? qp[(size_t)(l0 + 1) * HW] : 0.f;
            Ssum += fabsf(v0) + fabsf(v1);
            unsigned h0 = bf16rn(v0), h1 = bf16rn(v1);
            float r0 = v0 - __uint_as_float(h0 << 16);
            float r1 = v1 - __uint_as_float(h1 << 16);
            wh[j] = h0 | (h1 << 16);
            wl[j] = bf16rn(r0) | (bf16rn(r1) << 16);
        }
        qh[ks].u4 = make_uint4(wh[0], wh[1], wh[2], wh[3]);
        ql[ks].u4 = make_uint4(wl[0], wl[1], wl[2], wl[3]);
    }
    const float S_p = Ssum + __shfl_xor(Ssum, 32);   // full sum over 72
    const float kmax = __uint_as_float(ctrl[1]);

    float b1 = -3.0e38f, b2 = -3.0e38f;
    int bi = 0;

    // prologue: stage group 0
#pragma unroll
    for (int j = 0; j < 5; ++j)
        kbuf[0][tid + j * 256] = kfg[tid + j * 256];
    __syncthreads();

    for (int g = 0; g < NG; ++g) {
        const int cur = g & 1;
        if (g < NG - 1) {
#pragma unroll
            for (int j = 0; j < 5; ++j)
                kbuf[cur ^ 1][tid + j * 256] = kfg[(size_t)(g + 1) * 1280 + tid + j * 256];
        }
        const uint4* kb = kbuf[cur];
        do_tile<false>(kb, 0, 2 * g, qh, ql, lane, hb, b1, b2, bi);
        if (g == NG - 1) do_tile<true >(kb, 1, 2 * g + 1, qh, ql, lane, hb, b1, b2, bi);
        else             do_tile<false>(kb, 1, 2 * g + 1, qh, ql, lane, hb, b1, b2, bi);
        __syncthreads();
    }

    // merge key-halves: lane p <-> lane p+32 hold same pixel, disjoint keys
    const float ob1 = __shfl_xor(b1, 32);
    const float ob2 = __shfl_xor(b2, 32);
    const int   obi = __shfl_xor(bi, 32);
    const float nb2 = fmaxf(fminf(b1, ob1), fmaxf(b2, ob2));
    const bool take = (ob1 > b1) || (ob1 == b1 && obi < bi);
    const float nb1 = fmaxf(b1, ob1);
    const int  nbi = take ? obi : bi;

    // certainty: exact f32 gap vs rigorous error window (no quantization slop)
    const float thr = 2.0f * (CERR * S_p * kmax + ABSG);
    const bool certain = ((nb1 - nb2) > thr);

    if ((lane & 32) == 0) {
        if (certain) idx_buf[p] = nbi;
        else { unsigned pos = atomicAdd(&ctrl[0], 1u); list[pos] = (unsigned)p; }
    }
}

// -------- cleanup: exact f32 rescore, one WAVE per uncertain pixel --------
// grid = 128 blocks x 256 (512 waves), grid-stride over the list.
__global__ __launch_bounds__(256) void cleanup_kernel(
    const float* __restrict__ queries, const float* __restrict__ keys,
    const unsigned* __restrict__ ctrl, const unsigned* __restrict__ list,
    int* __restrict__ idx_buf)
{
    const int ln = threadIdx.x & 63;
    const unsigned count = ctrl[0];
    const unsigned wstride = gridDim.x * 4;
    for (unsigned wv = blockIdx.x * 4 + (threadIdx.x >> 6); wv < count; wv += wstride) {
        const int p  = (int)list[wv];
        const int b  = p / HW;
        const int hw = p - b * HW;
        const float* __restrict__ qp = queries + (size_t)b * LL * HW + hw;

        // wave-uniform addresses -> scalar loads; q lives in SGPRs
        float q[LL];
#pragma unroll
        for (int l = 0; l < LL; ++l) q[l] = qp[(size_t)l * HW];

        float best = -3.0e38f; int bidx = 0x7FFFFFFF;
#pragma unroll 1
        for (int n0 = 0; n0 < NKPAD; n0 += 64) {
            const int n  = n0 + ln;
            const int nc = (n < NKEYS) ? n : (NKEYS - 1);
            const float4* __restrict__ kr = (const float4*)(keys + (size_t)nc * LL);
            float a0 = 0.f, a1 = 0.f, a2 = 0.f, a3 = 0.f;
#pragma unroll
            for (int j = 0; j < 18; ++j) {
                float4 kv = kr[j];
                a0 = fmaf(q[4 * j + 0], kv.x, a0);
                a1 = fmaf(q[4 * j + 1], kv.y, a1);
                a2 = fmaf(q[4 * j + 2], kv.z, a2);
                a3 = fmaf(q[4 * j + 3], kv.w, a3);
            }
            const float s = (a0 + a1) + (a2 + a3);
            if (n < NKEYS && (s > best || (s == best && n < bidx))) { best = s; bidx = n; }
        }
#pragma unroll
        for (int m = 32; m >= 1; m >>= 1) {
            const float ob = __shfl_xor(best, m);
            const int   oi = __shfl_xor(bidx, m);
            if (ob > best || (ob == best && oi < bidx)) { best = ob; bidx = oi; }
        }
        if (ln == 0) idx_buf[p] = bidx;
    }
}

// ------- conv: gather + dynamic 5x5 conv + pixel shuffle -------
__global__ __launch_bounds__(256) void conv_kernel(
    const float* __restrict__ x,
    const float* __restrict__ values,
    const int* __restrict__ idx_buf,
    float* __restrict__ out)
{
    const int p  = blockIdx.x * 256 + threadIdx.x;
    const int b  = p / HW;
    const int hw = p - b * HW;
    const int h  = hw / W;
    const int w  = hw - h * W;

    const int idx = idx_buf[p];

    float patch[CC][25];
#pragma unroll
    for (int i = 0; i < 5; ++i) {
        int r = h + i - 2;
        r = (r < 0) ? -r : ((r >= H) ? (2 * H - 2 - r) : r);
#pragma unroll
        for (int j = 0; j < 5; ++j) {
            int cidx = w + j - 2;
            cidx = (cidx < 0) ? -cidx : ((cidx >= W) ? (2 * W - 2 - cidx) : cidx);
#pragma unroll
            for (int c = 0; c < CC; ++c)
                patch[c][i * 5 + j] = x[((size_t)(b * CC + c) * H + r) * W + cidx];
        }
    }

    const float* vbase = values + (size_t)idx * 400;
    float acc[CC][16];
#pragma unroll
    for (int c = 0; c < CC; ++c)
#pragma unroll
        for (int si = 0; si < 16; ++si) acc[c][si] = 0.f;

#pragma unroll
    for (int si = 0; si < 16; ++si) {
        float v[25];
#pragma unroll
        for (int kk = 0; kk < 25; ++kk) v[kk] = vbase[si * 25 + kk];
#pragma unroll
        for (int c = 0; c < CC; ++c) {
            float a = 0.f;
#pragma unroll
            for (int kk = 0; kk < 25; ++kk) a += patch[c][kk] * v[kk];
            acc[c][si] = a;
        }
    }

#pragma unroll
    for (int c = 0; c < CC; ++c) {
#pragma unroll
        for (int sy = 0; sy < 4; ++sy) {
            float4 o = make_float4(acc[c][sy * 4 + 0], acc[c][sy * 4 + 1],
                                   acc[c][sy * 4 + 2], acc[c][sy * 4 + 3]);
            size_t off = ((size_t)(b * CC + c) * (H * 4) + (h * 4 + sy)) * (size_t)(W * 4)
                         + (size_t)w * 4;
            *(float4*)(&out[off]) = o;
        }
    }
}

extern "C" void kernel_launch(void* const* d_in, const int* in_sizes, int n_in,
                              void* d_out, int out_size, void* d_ws, size_t ws_size,
                              hipStream_t stream) {
    const float* x       = (const float*)d_in[0];
    const float* queries = (const float*)d_in[1];
    const float* keys    = (const float*)d_in[2];
    const float* values  = (const float*)d_in[3];
    float* out = (float*)d_out;

    char* ws = (char*)d_ws;
    unsigned* ctrl   = (unsigned*)ws;
    uint4*    kfg    = (uint4*)(ws + WS_KFRAG);
    unsigned* list   = (unsigned*)(ws + WS_LIST);
    int*      idxb   = (int*)(ws + WS_IDX);

    hipMemsetAsync(d_ws, 0, 8, stream);
    kprep_kernel<<<NT, 64, 0, stream>>>(keys, ctrl, kfg);
    route_kernel<<<NPIX / 128, 256, 0, stream>>>(queries, kfg, ctrl, list, idxb);
    cleanup_kernel<<<128, 256, 0, stream>>>(queries, keys, ctrl, list, idxb);
    conv_kernel<<<NPIX / 256, 256, 0, stream>>>(x, values, idxb, out);
}